// Round 5
// baseline (189.018 us; speedup 1.0000x reference)
//
#include <hip/hip_runtime.h>
#include <hip/hip_bf16.h>
#include <math.h>

#define BATCH  2
#define S_LEN  2048
#define DMODEL 1024
#define NH     16
#define DHEAD  64

typedef __attribute__((ext_vector_type(8))) short bf16x8;   // 8 bf16 = 4 VGPRs
typedef __attribute__((ext_vector_type(4))) float f32x4;

#define MFMA16(a,b,c) __builtin_amdgcn_mfma_f32_16x16x32_bf16((a),(b),(c),0,0,0)

// Q pre-scale: (1/sqrt(64)) * log2(e) so attention uses exp2 directly
#define QSCALE 0.18033688011110793f
#define EXP2F(x) __builtin_amdgcn_exp2f(x)

__device__ __forceinline__ unsigned int pkbf(float a, float b) {
    __hip_bfloat162 h = __float22bfloat162_rn(make_float2(a, b));
    union { __hip_bfloat162 h; unsigned int u; } v; v.h = h; return v.u;
}
__device__ __forceinline__ void gl2lds16(const void* g, void* l) {
    __builtin_amdgcn_global_load_lds(
        (const __attribute__((address_space(1))) void*)(g),
        (__attribute__((address_space(3))) void*)(l), 16, 0, 0);
}

// ---------------------------------------------------------------------------
// Single fused fp32->bf16 convert for Q, W_Q|W_K|W_V, mask. 8 elems/unit.
// ---------------------------------------------------------------------------
__global__ __launch_bounds__(256) void cvt_all(
    const float* __restrict__ Q,  const float* __restrict__ WQ,
    const float* __restrict__ WK, const float* __restrict__ WV,
    const float* __restrict__ msk,
    unsigned short* __restrict__ Qbf, unsigned short* __restrict__ Wbf,
    unsigned short* __restrict__ mbf)
{
    int i = blockIdx.x * blockDim.x + threadIdx.x;   // grid covers 918016 units
    const float* src;
    unsigned short* dst;
    int off;
    if (i < 524288) {
        src = Q; dst = Qbf; off = i;
    } else if (i < 917504) {
        int j = i - 524288;                  // [0, 393216)
        int which = j >> 17;                 // /131072
        src = (which == 0) ? WQ : ((which == 1) ? WK : WV);
        dst = Wbf + ((size_t)which << 20);   // which * 1048576
        off = j & 131071;
    } else {
        int j = i - 917504;
        if (j >= 512) return;
        src = msk; dst = mbf; off = j;
    }
    float4 a = ((const float4*)src)[2*off];
    float4 b = ((const float4*)src)[2*off + 1];
    uint4 o;
    o.x = pkbf(a.x, a.y); o.y = pkbf(a.z, a.w);
    o.z = pkbf(b.x, b.y); o.w = pkbf(b.z, b.w);
    ((uint4*)dst)[off] = o;
}

// ---------------------------------------------------------------------------
// Projection GEMM with folds (unchanged):
//   z=0 -> qw [b,h,s,dk] *QSCALE ; z=1 -> kw ; z=2 -> vt [b,h,dv,s] * mask
// 128x128 tile, BK=64, dbuf LDS, XOR-swizzle, XCD-bijective remap.
// ---------------------------------------------------------------------------
__global__ __launch_bounds__(256) void proj_mfma(
    const unsigned short* __restrict__ Abf,   // [4096][1024]
    const unsigned short* __restrict__ Wbf,   // [3][1024][1024]
    const float* __restrict__ bQ, const float* __restrict__ bK,
    const float* __restrict__ bV, const float* __restrict__ mask,
    unsigned short* __restrict__ qw, unsigned short* __restrict__ kw,
    unsigned short* __restrict__ vt)
{
    __shared__ union {
        struct { unsigned short At[2][128*64]; unsigned short Bt[2][128*64]; } s; // 64 KB
        unsigned short Ct[128*132];     // epilogue transpose tile (33.8 KB, aliased)
    } sm;

    const int tid  = threadIdx.x;
    const int lane = tid & 63;
    const int wv   = tid >> 6;
    const int wm   = (wv >> 1) * 64;
    const int wn   = (wv & 1) * 64;
    const int q15  = lane & 15;
    const int quad = lane >> 4;

    const int f  = blockIdx.x + (blockIdx.y << 3) + (blockIdx.z << 8);
    const int l  = (f & 7) * 96 + (f >> 3);
    const int z  = l >> 8;
    const int lr = l & 255;
    const int n0 = (lr & 7) * 128;
    const int m0 = (lr >> 3) * 128;

    const unsigned short* Wz = Wbf + (size_t)z * DMODEL * DMODEL;
    const float* bias = (z == 0) ? bQ : ((z == 1) ? bK : bV);

    f32x4 zero4 = {0.f, 0.f, 0.f, 0.f};
    f32x4 acc[4][4];
    #pragma unroll
    for (int i = 0; i < 4; ++i)
        #pragma unroll
        for (int j = 0; j < 4; ++j) acc[i][j] = zero4;

    #define STAGE_PROJ(BUF, K0)                                                \
        _Pragma("unroll")                                                      \
        for (int c = 0; c < 4; ++c) {                                          \
            int o   = tid * 16 + c * 4096;                                     \
            int row = o >> 7;                                                  \
            int lb  = (o & 127) ^ ((row & 7) << 4);                            \
            gl2lds16(Abf + (size_t)(m0 + row) * DMODEL + (K0) + (lb >> 1),     \
                     (char*)sm.s.At[BUF] + o);                                 \
            gl2lds16(Wz  + (size_t)(n0 + row) * DMODEL + (K0) + (lb >> 1),     \
                     (char*)sm.s.Bt[BUF] + o);                                 \
        }

    STAGE_PROJ(0, 0)
    __syncthreads();

    const int sw = (q15 & 7) << 4;

    for (int t = 0; t < 16; ++t) {
        const int buf = t & 1;
        if (t < 15) { STAGE_PROJ(buf ^ 1, (t + 1) * 64) }

        bf16x8 af[4][2], bfr[4][2];
        #pragma unroll
        for (int i = 0; i < 4; ++i) {
            const char* pa = (const char*)sm.s.At[buf] + (wm + i*16 + q15) * 128;
            const char* pb = (const char*)sm.s.Bt[buf] + (wn + i*16 + q15) * 128;
            af[i][0]  = *(const bf16x8*)(pa + (( 0 + quad*16) ^ sw));
            af[i][1]  = *(const bf16x8*)(pa + ((64 + quad*16) ^ sw));
            bfr[i][0] = *(const bf16x8*)(pb + (( 0 + quad*16) ^ sw));
            bfr[i][1] = *(const bf16x8*)(pb + ((64 + quad*16) ^ sw));
        }

        if (z < 2) {
            #pragma unroll
            for (int ks = 0; ks < 2; ++ks)
                #pragma unroll
                for (int i = 0; i < 4; ++i)
                    #pragma unroll
                    for (int j = 0; j < 4; ++j)
                        acc[i][j] = MFMA16(bfr[j][ks], af[i][ks], acc[i][j]);
        } else {
            #pragma unroll
            for (int ks = 0; ks < 2; ++ks)
                #pragma unroll
                for (int i = 0; i < 4; ++i)
                    #pragma unroll
                    for (int j = 0; j < 4; ++j)
                        acc[i][j] = MFMA16(af[i][ks], bfr[j][ks], acc[i][j]);
        }
        __syncthreads();
    }
    #undef STAGE_PROJ

    if (z < 2) {
        const float qs = (z == 0) ? QSCALE : 1.0f;
        #pragma unroll
        for (int i = 0; i < 4; ++i) {
            int ml = wm + i*16 + q15;
            #pragma unroll
            for (int j = 0; j < 4; ++j) {
                int nl = wn + j*16 + quad*4;
                float4 b4 = *(const float4*)(bias + n0 + nl);
                f32x4 v = acc[i][j];
                uint2 u;
                u.x = pkbf((v.x + b4.x)*qs, (v.y + b4.y)*qs);
                u.y = pkbf((v.z + b4.z)*qs, (v.w + b4.w)*qs);
                *(uint2*)&sm.Ct[ml*132 + nl] = u;
            }
        }
    } else {
        #pragma unroll
        for (int i = 0; i < 4; ++i) {
            int ml = wm + i*16 + quad*4;
            int sg = m0 + ml;
            int b2 = sg >> 11, s0g = sg & 2047;
            float4 mk4 = *(const float4*)(mask + (size_t)b2*S_LEN + s0g);
            #pragma unroll
            for (int j = 0; j < 4; ++j) {
                int nl = wn + j*16 + q15;
                float bv = bias[n0 + nl];
                f32x4 v = acc[i][j];
                uint2 u;
                u.x = pkbf((v.x + bv)*mk4.x, (v.y + bv)*mk4.y);
                u.y = pkbf((v.z + bv)*mk4.z, (v.w + bv)*mk4.w);
                *(uint2*)&sm.Ct[nl*132 + ml] = u;
            }
        }
    }
    __syncthreads();

    {
        int row  = tid >> 1;
        int half = (tid & 1) * 64;
        const uint4* src = (const uint4*)&sm.Ct[row*132 + half];
        unsigned short* dst;
        if (z < 2) {
            unsigned short* outp = (z == 0) ? qw : kw;
            int mg = m0 + row;  int b2 = mg >> 11, s = mg & 2047;
            int n  = n0 + half; int hh = n >> 6;
            dst = outp + (((size_t)b2*NH + hh)*S_LEN + s)*DHEAD;
        } else {
            int n  = n0 + row;  int hh = n >> 6, dv = n & 63;
            int b2 = m0 >> 11, s0 = m0 & 2047;
            dst = vt + (((size_t)b2*NH + hh)*DHEAD + dv)*S_LEN + s0 + half;
        }
        #pragma unroll
        for (int c = 0; c < 8; ++c) ((uint4*)dst)[c] = src[c];
    }
}

// ---------------------------------------------------------------------------
// Attention v5 (= v4 with the K-prefetch address bug fixed):
//   v4 bug: tile t+1 K source advanced by `kn` SHORTS; kw is [key][d] so a
//   key-tile step is kn*DHEAD shorts. (V/mask are key-contiguous, were fine.)
// Structure: block = 128 q, 4 waves x 32 q, grid 512, XCD-bijective remap.
//  * V read directly from global vt[dv][s] (L2-resident per-XCD), no LDS.
//  * K staged via global_load_lds, lambda-permutation AND XOR bank-swizzle
//    folded into per-lane GLOBAL source (linear LDS dest + swizzled read).
//  LDS row rho holds key invLambda(rho); QK D-layout then directly gives the
//  PV A-fragment after exp2+pack (key of reg r, tile ks, lane(quad,q15) =
//  quad*8 + r + 4*(ks&1) + 32*(ks>>1)).
// ---------------------------------------------------------------------------
__global__ __launch_bounds__(256, 2) void attn_mfma(
    const unsigned short* __restrict__ qw, const unsigned short* __restrict__ kw,
    const unsigned short* __restrict__ vt, const unsigned short* __restrict__ mbf,
    float* __restrict__ out)
{
    __shared__ __align__(16) unsigned short Ks[2][64][64];   // swizzled, 16 KB

    const int tid  = threadIdx.x;
    const int lane = tid & 63;
    const int wv   = tid >> 6;
    const int q15  = lane & 15;
    const int quad = lane >> 4;

    // XCD-bijective remap (512 = 8 XCDs x 64): XCD c owns heads [c*4, c*4+4).
    const int orig = blockIdx.x + (blockIdx.y << 4) + (blockIdx.z << 8);
    const int lid  = (orig & 7) * 64 + (orig >> 3);
    const int q0   = (lid & 15) * 128;
    const int head = lid >> 4;          // [0,32)
    const int h    = head & 15;
    const int b    = head >> 4;

    const size_t headoff = ((size_t)b * NH + h) * S_LEN * DHEAD;
    const unsigned short* qb = qw + headoff;
    const unsigned short* kb = kw + headoff;
    const unsigned short* vb = vt + headoff;          // [dv][s]
    const unsigned short* mb = mbf + (size_t)b * S_LEN;

    // Q fragments (B-operand): B[k=d at quad*8+j][n=query at lane&15]
    bf16x8 qf[2][2];
    #pragma unroll
    for (int qi = 0; qi < 2; ++qi) {
        const unsigned short* qr = qb + (size_t)(q0 + wv*32 + qi*16 + q15)*DHEAD;
        qf[qi][0] = *(const bf16x8*)(qr + quad*8);
        qf[qi][1] = *(const bf16x8*)(qr + 32 + quad*8);
    }

    // K staging addressing: dest byte o = tid*16 (+4096 for c=1); row = o>>7.
    // LDS row rho holds global key kap = invLambda(rho); source byte-in-row is
    // XOR-swizzled with ((rho&7)<<4) so swizzled READS return logical data.
    const int srow = tid >> 3;                        // 0..31 (= dest row, c=0)
    const int kap  = (srow & 3) | (((srow >> 4) & 1) << 2) | (((srow >> 2) & 3) << 3);
    const int lb   = ((tid & 7) * 16) ^ ((srow & 7) << 4);
    const unsigned short* ksrc0 = kb + (size_t)kap       * DHEAD + (lb >> 1);
    const unsigned short* ksrc1 = kb + (size_t)(kap + 32)* DHEAD + (lb >> 1);
    char* kdst0 = (char*)&Ks[0][0][0] + tid * 16;     // c=0; c=1 at +4096
    const int sw = (q15 & 7) << 4;                    // read-side swizzle

    // V row base pointers: lane (q15) owns dv rows nj*16+q15; quad*8 folds in.
    const unsigned short* vrow[4];
    #pragma unroll
    for (int nj = 0; nj < 4; ++nj)
        vrow[nj] = vb + (size_t)(nj*16 + q15) * S_LEN + quad*8;

    f32x4 zero4 = {0.f, 0.f, 0.f, 0.f};
    f32x4 oacc[2][4];
    f32x4 dacc[2];
    #pragma unroll
    for (int qi = 0; qi < 2; ++qi) {
        dacc[qi] = zero4;
        #pragma unroll
        for (int nj = 0; nj < 4; ++nj) oacc[qi][nj] = zero4;
    }

    // prologue: stage K tile 0; prefetch mask tile 0
    gl2lds16(ksrc0, kdst0);
    gl2lds16(ksrc1, kdst0 + 4096);
    bf16x8 mc0 = *(const bf16x8*)(mb + quad*8);
    bf16x8 mc1 = *(const bf16x8*)(mb + 32 + quad*8);

    for (int t = 0; t < 32; ++t) {
        const int buf = t & 1;
        const int k0  = t * 64;
        const int kn  = (t < 31) ? k0 + 64 : 0;

        __syncthreads();    // staging for tile t complete (had tile t-1 to land)

        // current-tile V fragments: direct from global (L2); consumed in PV
        bf16x8 vf[4][2];
        #pragma unroll
        for (int nj = 0; nj < 4; ++nj) {
            vf[nj][0] = *(const bf16x8*)(vrow[nj] + k0);
            vf[nj][1] = *(const bf16x8*)(vrow[nj] + k0 + 32);
        }
        // prefetch K tile t+1 into other buffer (drained at next barrier).
        // NOTE: key-tile step on kw[key][d] is kn*DHEAD shorts (v4 bug: +kn).
        if (t < 31) {
            gl2lds16(ksrc0 + (size_t)kn * DHEAD, kdst0 + (buf ^ 1) * 8192);
            gl2lds16(ksrc1 + (size_t)kn * DHEAD, kdst0 + (buf ^ 1) * 8192 + 4096);
        }
        // prefetch mask for tile t+1 (mask is key-contiguous: +kn correct)
        bf16x8 mn0 = *(const bf16x8*)(mb + kn + quad*8);
        bf16x8 mn1 = *(const bf16x8*)(mb + kn + 32 + quad*8);

        // ---- QK^T from swizzled Ks ----
        const char* kbase = (const char*)&Ks[0][0][0] + buf * 8192;
        f32x4 s[2][4];
        __builtin_amdgcn_s_setprio(1);
        #pragma unroll
        for (int ks = 0; ks < 4; ++ks) {
            const char* krp = kbase + (ks*16 + q15) * 128;
            bf16x8 kf0 = *(const bf16x8*)(krp + (( 0 + quad*16) ^ sw));
            bf16x8 kf1 = *(const bf16x8*)(krp + ((64 + quad*16) ^ sw));
            #pragma unroll
            for (int qi = 0; qi < 2; ++qi) {
                f32x4 a = MFMA16(kf0, qf[qi][0], zero4);
                s[qi][ks] = MFMA16(kf1, qf[qi][1], a);
            }
        }
        __builtin_amdgcn_s_setprio(0);
        // ---- exp2 + pack: registers ARE the PV A-fragments ----
        bf16x8 pf[2][2];
        #pragma unroll
        for (int qi = 0; qi < 2; ++qi) {
            uint4 u0, u1;
            u0.x = pkbf(EXP2F(s[qi][0][0]), EXP2F(s[qi][0][1]));
            u0.y = pkbf(EXP2F(s[qi][0][2]), EXP2F(s[qi][0][3]));
            u0.z = pkbf(EXP2F(s[qi][1][0]), EXP2F(s[qi][1][1]));
            u0.w = pkbf(EXP2F(s[qi][1][2]), EXP2F(s[qi][1][3]));
            u1.x = pkbf(EXP2F(s[qi][2][0]), EXP2F(s[qi][2][1]));
            u1.y = pkbf(EXP2F(s[qi][2][2]), EXP2F(s[qi][2][3]));
            u1.z = pkbf(EXP2F(s[qi][3][0]), EXP2F(s[qi][3][1]));
            u1.w = pkbf(EXP2F(s[qi][3][2]), EXP2F(s[qi][3][3]));
            union { uint4 u; bf16x8 h; } c0, c1;
            c0.u = u0; c1.u = u1;
            pf[qi][0] = c0.h;   // keys quad*8+0..7
            pf[qi][1] = c1.h;   // keys 32+quad*8+0..7
        }
        // ---- denominator (mask in regs) + PV (V direct from global) ----
        __builtin_amdgcn_s_setprio(1);
        #pragma unroll
        for (int qi = 0; qi < 2; ++qi) {
            dacc[qi] = MFMA16(pf[qi][0], mc0, dacc[qi]);
            dacc[qi] = MFMA16(pf[qi][1], mc1, dacc[qi]);
        }
        #pragma unroll
        for (int nj = 0; nj < 4; ++nj) {
            #pragma unroll
            for (int qi = 0; qi < 2; ++qi) {
                oacc[qi][nj] = MFMA16(pf[qi][0], vf[nj][0], oacc[qi][nj]);
                oacc[qi][nj] = MFMA16(pf[qi][1], vf[nj][1], oacc[qi][nj]);
            }
        }
        __builtin_amdgcn_s_setprio(0);
        mc0 = mn0; mc1 = mn1;
    }

    // epilogue: D rows quad*4+r = query; denom replicated across n lanes
    #pragma unroll
    for (int qi = 0; qi < 2; ++qi)
        #pragma unroll
        for (int r = 0; r < 4; ++r) {
            float inv = 1.0f / (dacc[qi][r] + 1e-8f);
            size_t row = ((size_t)b*S_LEN + q0 + wv*32 + qi*16 + quad*4 + r)*DMODEL
                       + h*DHEAD;
            #pragma unroll
            for (int nj = 0; nj < 4; ++nj)
                out[row + nj*16 + q15] = oacc[qi][nj][r] * inv;
        }
}

// ---------------------------------------------------------------------------
extern "C" void kernel_launch(void* const* d_in, const int* in_sizes, int n_in,
                              void* d_out, int out_size, void* d_ws, size_t ws_size,
                              hipStream_t stream) {
    const float* Q    = (const float*)d_in[0];
    const float* msk  = (const float*)d_in[1];
    const float* W_Q  = (const float*)d_in[2];
    const float* b_Q  = (const float*)d_in[3];
    const float* W_K  = (const float*)d_in[4];
    const float* b_K  = (const float*)d_in[5];
    const float* W_V  = (const float*)d_in[6];
    const float* b_V  = (const float*)d_in[7];
    float* out = (float*)d_out;

    unsigned short* wsu = (unsigned short*)d_ws;
    unsigned short* Qbf = wsu;                                   // 4M elems
    unsigned short* Wbf = Qbf + (size_t)4096*1024;               // 3M
    unsigned short* qwb = Wbf + (size_t)3*1024*1024;             // 4M
    unsigned short* kwb = qwb + (size_t)4*1024*1024;             // 4M
    unsigned short* vtb = kwb + (size_t)4*1024*1024;             // 4M
    unsigned short* mbf = vtb + (size_t)4*1024*1024;             // 4K

    cvt_all<<<3586, 256, 0, stream>>>(Q, W_Q, W_K, W_V, msk, Qbf, Wbf, mbf);

    proj_mfma<<<dim3(8, 32, 3), 256, 0, stream>>>(
        Qbf, Wbf, b_Q, b_K, b_V, msk, qwb, kwb, vtb);

    attn_mfma<<<dim3(S_LEN/128, NH, BATCH), 256, 0, stream>>>(
        qwb, kwb, vtb, mbf, out);
}

// Round 6
// 169.233 us; speedup vs baseline: 1.1169x; 1.1169x over previous
//
#include <hip/hip_runtime.h>
#include <hip/hip_bf16.h>
#include <math.h>

#define BATCH  2
#define S_LEN  2048
#define DMODEL 1024
#define NH     16
#define DHEAD  64

typedef __attribute__((ext_vector_type(8))) short bf16x8;   // 8 bf16 = 4 VGPRs
typedef __attribute__((ext_vector_type(4))) float f32x4;

#define MFMA16(a,b,c) __builtin_amdgcn_mfma_f32_16x16x32_bf16((a),(b),(c),0,0,0)

// Q pre-scale: (1/sqrt(64)) * log2(e) so attention uses exp2 directly
#define QSCALE 0.18033688011110793f
#define EXP2F(x) __builtin_amdgcn_exp2f(x)

__device__ __forceinline__ unsigned int pkbf(float a, float b) {
    __hip_bfloat162 h = __float22bfloat162_rn(make_float2(a, b));
    union { __hip_bfloat162 h; unsigned int u; } v; v.h = h; return v.u;
}
__device__ __forceinline__ void gl2lds16(const void* g, void* l) {
    __builtin_amdgcn_global_load_lds(
        (const __attribute__((address_space(1))) void*)(g),
        (__attribute__((address_space(3))) void*)(l), 16, 0, 0);
}

// ---------------------------------------------------------------------------
// Single fused fp32->bf16 convert for Q, W_Q|W_K|W_V, mask. 8 elems/unit.
// ---------------------------------------------------------------------------
__global__ __launch_bounds__(256) void cvt_all(
    const float* __restrict__ Q,  const float* __restrict__ WQ,
    const float* __restrict__ WK, const float* __restrict__ WV,
    const float* __restrict__ msk,
    unsigned short* __restrict__ Qbf, unsigned short* __restrict__ Wbf,
    unsigned short* __restrict__ mbf)
{
    int i = blockIdx.x * blockDim.x + threadIdx.x;   // grid covers 918016 units
    const float* src;
    unsigned short* dst;
    int off;
    if (i < 524288) {
        src = Q; dst = Qbf; off = i;
    } else if (i < 917504) {
        int j = i - 524288;                  // [0, 393216)
        int which = j >> 17;                 // /131072
        src = (which == 0) ? WQ : ((which == 1) ? WK : WV);
        dst = Wbf + ((size_t)which << 20);   // which * 1048576
        off = j & 131071;
    } else {
        int j = i - 917504;
        if (j >= 512) return;
        src = msk; dst = mbf; off = j;
    }
    float4 a = ((const float4*)src)[2*off];
    float4 b = ((const float4*)src)[2*off + 1];
    uint4 o;
    o.x = pkbf(a.x, a.y); o.y = pkbf(a.z, a.w);
    o.z = pkbf(b.x, b.y); o.w = pkbf(b.z, b.w);
    ((uint4*)dst)[off] = o;
}

// ---------------------------------------------------------------------------
// Projection GEMM with folds (unchanged):
//   z=0 -> qw [b,h,s,dk] *QSCALE ; z=1 -> kw ; z=2 -> vt [b,h,dv,s] * mask
// 128x128 tile, BK=64, dbuf LDS, XOR-swizzle, XCD-bijective remap.
// ---------------------------------------------------------------------------
__global__ __launch_bounds__(256) void proj_mfma(
    const unsigned short* __restrict__ Abf,   // [4096][1024]
    const unsigned short* __restrict__ Wbf,   // [3][1024][1024]
    const float* __restrict__ bQ, const float* __restrict__ bK,
    const float* __restrict__ bV, const float* __restrict__ mask,
    unsigned short* __restrict__ qw, unsigned short* __restrict__ kw,
    unsigned short* __restrict__ vt)
{
    __shared__ union {
        struct { unsigned short At[2][128*64]; unsigned short Bt[2][128*64]; } s; // 64 KB
        unsigned short Ct[128*132];     // epilogue transpose tile (33.8 KB, aliased)
    } sm;

    const int tid  = threadIdx.x;
    const int lane = tid & 63;
    const int wv   = tid >> 6;
    const int wm   = (wv >> 1) * 64;
    const int wn   = (wv & 1) * 64;
    const int q15  = lane & 15;
    const int quad = lane >> 4;

    const int f  = blockIdx.x + (blockIdx.y << 3) + (blockIdx.z << 8);
    const int l  = (f & 7) * 96 + (f >> 3);
    const int z  = l >> 8;
    const int lr = l & 255;
    const int n0 = (lr & 7) * 128;
    const int m0 = (lr >> 3) * 128;

    const unsigned short* Wz = Wbf + (size_t)z * DMODEL * DMODEL;
    const float* bias = (z == 0) ? bQ : ((z == 1) ? bK : bV);

    f32x4 zero4 = {0.f, 0.f, 0.f, 0.f};
    f32x4 acc[4][4];
    #pragma unroll
    for (int i = 0; i < 4; ++i)
        #pragma unroll
        for (int j = 0; j < 4; ++j) acc[i][j] = zero4;

    #define STAGE_PROJ(BUF, K0)                                                \
        _Pragma("unroll")                                                      \
        for (int c = 0; c < 4; ++c) {                                          \
            int o   = tid * 16 + c * 4096;                                     \
            int row = o >> 7;                                                  \
            int lb  = (o & 127) ^ ((row & 7) << 4);                            \
            gl2lds16(Abf + (size_t)(m0 + row) * DMODEL + (K0) + (lb >> 1),     \
                     (char*)sm.s.At[BUF] + o);                                 \
            gl2lds16(Wz  + (size_t)(n0 + row) * DMODEL + (K0) + (lb >> 1),     \
                     (char*)sm.s.Bt[BUF] + o);                                 \
        }

    STAGE_PROJ(0, 0)
    __syncthreads();

    const int sw = (q15 & 7) << 4;

    for (int t = 0; t < 16; ++t) {
        const int buf = t & 1;
        if (t < 15) { STAGE_PROJ(buf ^ 1, (t + 1) * 64) }

        bf16x8 af[4][2], bfr[4][2];
        #pragma unroll
        for (int i = 0; i < 4; ++i) {
            const char* pa = (const char*)sm.s.At[buf] + (wm + i*16 + q15) * 128;
            const char* pb = (const char*)sm.s.Bt[buf] + (wn + i*16 + q15) * 128;
            af[i][0]  = *(const bf16x8*)(pa + (( 0 + quad*16) ^ sw));
            af[i][1]  = *(const bf16x8*)(pa + ((64 + quad*16) ^ sw));
            bfr[i][0] = *(const bf16x8*)(pb + (( 0 + quad*16) ^ sw));
            bfr[i][1] = *(const bf16x8*)(pb + ((64 + quad*16) ^ sw));
        }

        if (z < 2) {
            #pragma unroll
            for (int ks = 0; ks < 2; ++ks)
                #pragma unroll
                for (int i = 0; i < 4; ++i)
                    #pragma unroll
                    for (int j = 0; j < 4; ++j)
                        acc[i][j] = MFMA16(bfr[j][ks], af[i][ks], acc[i][j]);
        } else {
            #pragma unroll
            for (int ks = 0; ks < 2; ++ks)
                #pragma unroll
                for (int i = 0; i < 4; ++i)
                    #pragma unroll
                    for (int j = 0; j < 4; ++j)
                        acc[i][j] = MFMA16(af[i][ks], bfr[j][ks], acc[i][j]);
        }
        __syncthreads();
    }
    #undef STAGE_PROJ

    if (z < 2) {
        const float qs = (z == 0) ? QSCALE : 1.0f;
        #pragma unroll
        for (int i = 0; i < 4; ++i) {
            int ml = wm + i*16 + q15;
            #pragma unroll
            for (int j = 0; j < 4; ++j) {
                int nl = wn + j*16 + quad*4;
                float4 b4 = *(const float4*)(bias + n0 + nl);
                f32x4 v = acc[i][j];
                uint2 u;
                u.x = pkbf((v.x + b4.x)*qs, (v.y + b4.y)*qs);
                u.y = pkbf((v.z + b4.z)*qs, (v.w + b4.w)*qs);
                *(uint2*)&sm.Ct[ml*132 + nl] = u;
            }
        }
    } else {
        #pragma unroll
        for (int i = 0; i < 4; ++i) {
            int ml = wm + i*16 + quad*4;
            int sg = m0 + ml;
            int b2 = sg >> 11, s0g = sg & 2047;
            float4 mk4 = *(const float4*)(mask + (size_t)b2*S_LEN + s0g);
            #pragma unroll
            for (int j = 0; j < 4; ++j) {
                int nl = wn + j*16 + q15;
                float bv = bias[n0 + nl];
                f32x4 v = acc[i][j];
                uint2 u;
                u.x = pkbf((v.x + bv)*mk4.x, (v.y + bv)*mk4.y);
                u.y = pkbf((v.z + bv)*mk4.z, (v.w + bv)*mk4.w);
                *(uint2*)&sm.Ct[nl*132 + ml] = u;
            }
        }
    }
    __syncthreads();

    {
        int row  = tid >> 1;
        int half = (tid & 1) * 64;
        const uint4* src = (const uint4*)&sm.Ct[row*132 + half];
        unsigned short* dst;
        if (z < 2) {
            unsigned short* outp = (z == 0) ? qw : kw;
            int mg = m0 + row;  int b2 = mg >> 11, s = mg & 2047;
            int n  = n0 + half; int hh = n >> 6;
            dst = outp + (((size_t)b2*NH + hh)*S_LEN + s)*DHEAD;
        } else {
            int n  = n0 + row;  int hh = n >> 6, dv = n & 63;
            int b2 = m0 >> 11, s0 = m0 & 2047;
            dst = vt + (((size_t)b2*NH + hh)*DHEAD + dv)*S_LEN + s0 + half;
        }
        #pragma unroll
        for (int c = 0; c < 8; ++c) ((uint4*)dst)[c] = src[c];
    }
}

// ---------------------------------------------------------------------------
// Attention v6: combine the PROVEN halves of r3 and r5.
//  * r5 proved: gl2lds staging with swizzle folded into the per-lane GLOBAL
//    source is conflict-free (SQ_LDS_BANK_CONFLICT = 0). Keep for K.
//  * r5 disproved: V-direct-from-global (16-line L2 scatter latency on PV's
//    critical path every tile; 50.3 -> 76.2 us). V goes BACK to LDS, but now
//    staged via the same gl2lds+swizzle path (no reg round-trip, no ds_write,
//    no conflicts). vt is [dv][s]: V rows map linearly (no permutation) and
//    the key-tile step is +kn SHORTS (contiguous axis). K is [key][d]: step
//    is +kn*DHEAD (row axis). Mask: +kn.
// Structure: block = 128 q, 4 waves x 32 q, grid 512, XCD-bijective remap,
// double-buffered Ks/Vs (32 KB), ONE barrier per tile, setprio on MFMA.
// LDS row rho of Ks holds key invLambda(rho); QK D-layout after exp2+pack IS
// the PV A-fragment (key of reg r, tile ks, lane(quad,q15) =
// quad*8 + r + 4*(ks&1) + 32*(ks>>1)).
// ---------------------------------------------------------------------------
__global__ __launch_bounds__(256, 2) void attn_mfma(
    const unsigned short* __restrict__ qw, const unsigned short* __restrict__ kw,
    const unsigned short* __restrict__ vt, const unsigned short* __restrict__ mbf,
    float* __restrict__ out)
{
    __shared__ __align__(16) unsigned short Ks[2][64][64];   // swizzled, 16 KB
    __shared__ __align__(16) unsigned short Vs[2][64][64];   // swizzled, 16 KB

    const int tid  = threadIdx.x;
    const int lane = tid & 63;
    const int wv   = tid >> 6;
    const int q15  = lane & 15;
    const int quad = lane >> 4;

    // XCD-bijective remap (512 = 8 XCDs x 64): XCD c owns heads [c*4, c*4+4).
    const int orig = blockIdx.x + (blockIdx.y << 4) + (blockIdx.z << 8);
    const int lid  = (orig & 7) * 64 + (orig >> 3);
    const int q0   = (lid & 15) * 128;
    const int head = lid >> 4;          // [0,32)
    const int h    = head & 15;
    const int b    = head >> 4;

    const size_t headoff = ((size_t)b * NH + h) * S_LEN * DHEAD;
    const unsigned short* qb = qw + headoff;
    const unsigned short* kb = kw + headoff;
    const unsigned short* vb = vt + headoff;          // [dv][s]
    const unsigned short* mb = mbf + (size_t)b * S_LEN;

    // Q fragments (B-operand): B[k=d at quad*8+j][n=query at lane&15]
    bf16x8 qf[2][2];
    #pragma unroll
    for (int qi = 0; qi < 2; ++qi) {
        const unsigned short* qr = qb + (size_t)(q0 + wv*32 + qi*16 + q15)*DHEAD;
        qf[qi][0] = *(const bf16x8*)(qr + quad*8);
        qf[qi][1] = *(const bf16x8*)(qr + 32 + quad*8);
    }

    // Staging addressing (per thread): dest byte o = tid*16 (c=0), +4096 (c=1);
    // dest row = o>>7. Physical byte p of row r holds logical byte
    // p ^ ((r&7)<<4)  ->  source byte-in-row lb = ((tid&7)*16) ^ ((srow&7)<<4)
    // (srow&7 == (srow+32)&7, so lb serves both chunks).
    const int srow = tid >> 3;                        // 0..31
    const int kap  = (srow & 3) | (((srow >> 4) & 1) << 2) | (((srow >> 2) & 3) << 3);
    const int lb   = ((tid & 7) * 16) ^ ((srow & 7) << 4);
    const unsigned short* ksrc0 = kb + (size_t)kap        * DHEAD + (lb >> 1);
    const unsigned short* ksrc1 = kb + (size_t)(kap + 32) * DHEAD + (lb >> 1);
    const unsigned short* vsrc0 = vb + (size_t)srow        * S_LEN + (lb >> 1);
    const unsigned short* vsrc1 = vb + (size_t)(srow + 32) * S_LEN + (lb >> 1);
    char* kdst = (char*)&Ks[0][0][0] + tid * 16;      // c=0; c=1 at +4096
    char* vdst = (char*)&Vs[0][0][0] + tid * 16;
    const int sw = (q15 & 7) << 4;                    // read-side swizzle

    f32x4 zero4 = {0.f, 0.f, 0.f, 0.f};
    f32x4 oacc[2][4];
    f32x4 dacc[2];
    #pragma unroll
    for (int qi = 0; qi < 2; ++qi) {
        dacc[qi] = zero4;
        #pragma unroll
        for (int nj = 0; nj < 4; ++nj) oacc[qi][nj] = zero4;
    }

    // prologue: stage tile 0 into buf 0; prefetch mask tile 0
    gl2lds16(ksrc0, kdst);
    gl2lds16(ksrc1, kdst + 4096);
    gl2lds16(vsrc0, vdst);
    gl2lds16(vsrc1, vdst + 4096);
    bf16x8 mc0 = *(const bf16x8*)(mb + quad*8);
    bf16x8 mc1 = *(const bf16x8*)(mb + 32 + quad*8);

    for (int t = 0; t < 32; ++t) {
        const int buf = t & 1;
        const int kn  = (t < 31) ? (t + 1) * 64 : 0;

        __syncthreads();    // staging for tile t complete (had a full tile to land)

        // prefetch tile t+1 into other buffer (drained at next barrier).
        // Axis check: K is [key][d] -> +kn*DHEAD; V is [dv][s] -> +kn; mask +kn.
        if (t < 31) {
            const int ob = (buf ^ 1) * 8192;
            gl2lds16(ksrc0 + (size_t)kn * DHEAD, kdst + ob);
            gl2lds16(ksrc1 + (size_t)kn * DHEAD, kdst + ob + 4096);
            gl2lds16(vsrc0 + kn, vdst + ob);
            gl2lds16(vsrc1 + kn, vdst + ob + 4096);
        }
        bf16x8 mn0 = *(const bf16x8*)(mb + kn + quad*8);
        bf16x8 mn1 = *(const bf16x8*)(mb + kn + 32 + quad*8);

        // ---- QK^T from swizzled Ks ----
        const char* kbase = (const char*)&Ks[0][0][0] + buf * 8192;
        f32x4 s[2][4];
        __builtin_amdgcn_s_setprio(1);
        #pragma unroll
        for (int ks = 0; ks < 4; ++ks) {
            const char* krp = kbase + (ks*16 + q15) * 128;
            bf16x8 kf0 = *(const bf16x8*)(krp + (( 0 + quad*16) ^ sw));
            bf16x8 kf1 = *(const bf16x8*)(krp + ((64 + quad*16) ^ sw));
            #pragma unroll
            for (int qi = 0; qi < 2; ++qi) {
                f32x4 a = MFMA16(kf0, qf[qi][0], zero4);
                s[qi][ks] = MFMA16(kf1, qf[qi][1], a);
            }
        }
        __builtin_amdgcn_s_setprio(0);
        // ---- exp2 + pack: registers ARE the PV A-fragments ----
        bf16x8 pf[2][2];
        #pragma unroll
        for (int qi = 0; qi < 2; ++qi) {
            uint4 u0, u1;
            u0.x = pkbf(EXP2F(s[qi][0][0]), EXP2F(s[qi][0][1]));
            u0.y = pkbf(EXP2F(s[qi][0][2]), EXP2F(s[qi][0][3]));
            u0.z = pkbf(EXP2F(s[qi][1][0]), EXP2F(s[qi][1][1]));
            u0.w = pkbf(EXP2F(s[qi][1][2]), EXP2F(s[qi][1][3]));
            u1.x = pkbf(EXP2F(s[qi][2][0]), EXP2F(s[qi][2][1]));
            u1.y = pkbf(EXP2F(s[qi][2][2]), EXP2F(s[qi][2][3]));
            u1.z = pkbf(EXP2F(s[qi][3][0]), EXP2F(s[qi][3][1]));
            u1.w = pkbf(EXP2F(s[qi][3][2]), EXP2F(s[qi][3][3]));
            union { uint4 u; bf16x8 h; } c0, c1;
            c0.u = u0; c1.u = u1;
            pf[qi][0] = c0.h;   // keys quad*8+0..7
            pf[qi][1] = c1.h;   // keys 32+quad*8+0..7
        }
        // ---- denominator (mask in regs) + PV (V from swizzled Vs) ----
        const char* vbase = (const char*)&Vs[0][0][0] + buf * 8192;
        __builtin_amdgcn_s_setprio(1);
        #pragma unroll
        for (int qi = 0; qi < 2; ++qi) {
            dacc[qi] = MFMA16(pf[qi][0], mc0, dacc[qi]);
            dacc[qi] = MFMA16(pf[qi][1], mc1, dacc[qi]);
        }
        #pragma unroll
        for (int nj = 0; nj < 4; ++nj) {
            const char* vrp = vbase + (nj*16 + q15) * 128;
            bf16x8 vf0 = *(const bf16x8*)(vrp + (( 0 + quad*16) ^ sw));
            bf16x8 vf1 = *(const bf16x8*)(vrp + ((64 + quad*16) ^ sw));
            #pragma unroll
            for (int qi = 0; qi < 2; ++qi) {
                oacc[qi][nj] = MFMA16(pf[qi][0], vf0, oacc[qi][nj]);
                oacc[qi][nj] = MFMA16(pf[qi][1], vf1, oacc[qi][nj]);
            }
        }
        __builtin_amdgcn_s_setprio(0);
        mc0 = mn0; mc1 = mn1;
    }

    // epilogue: D rows quad*4+r = query; denom replicated across n lanes
    #pragma unroll
    for (int qi = 0; qi < 2; ++qi)
        #pragma unroll
        for (int r = 0; r < 4; ++r) {
            float inv = 1.0f / (dacc[qi][r] + 1e-8f);
            size_t row = ((size_t)b*S_LEN + q0 + wv*32 + qi*16 + quad*4 + r)*DMODEL
                       + h*DHEAD;
            #pragma unroll
            for (int nj = 0; nj < 4; ++nj)
                out[row + nj*16 + q15] = oacc[qi][nj][r] * inv;
        }
}

// ---------------------------------------------------------------------------
extern "C" void kernel_launch(void* const* d_in, const int* in_sizes, int n_in,
                              void* d_out, int out_size, void* d_ws, size_t ws_size,
                              hipStream_t stream) {
    const float* Q    = (const float*)d_in[0];
    const float* msk  = (const float*)d_in[1];
    const float* W_Q  = (const float*)d_in[2];
    const float* b_Q  = (const float*)d_in[3];
    const float* W_K  = (const float*)d_in[4];
    const float* b_K  = (const float*)d_in[5];
    const float* W_V  = (const float*)d_in[6];
    const float* b_V  = (const float*)d_in[7];
    float* out = (float*)d_out;

    unsigned short* wsu = (unsigned short*)d_ws;
    unsigned short* Qbf = wsu;                                   // 4M elems
    unsigned short* Wbf = Qbf + (size_t)4096*1024;               // 3M
    unsigned short* qwb = Wbf + (size_t)3*1024*1024;             // 4M
    unsigned short* kwb = qwb + (size_t)4*1024*1024;             // 4M
    unsigned short* vtb = kwb + (size_t)4*1024*1024;             // 4M
    unsigned short* mbf = vtb + (size_t)4*1024*1024;             // 4K

    cvt_all<<<3586, 256, 0, stream>>>(Q, W_Q, W_K, W_V, msk, Qbf, Wbf, mbf);

    proj_mfma<<<dim3(8, 32, 3), 256, 0, stream>>>(
        Qbf, Wbf, b_Q, b_K, b_V, msk, qwb, kwb, vtb);

    attn_mfma<<<dim3(S_LEN/128, NH, BATCH), 256, 0, stream>>>(
        qwb, kwb, vtb, mbf, out);
}

// Round 7
// 165.686 us; speedup vs baseline: 1.1408x; 1.0214x over previous
//
#include <hip/hip_runtime.h>
#include <hip/hip_bf16.h>
#include <math.h>

#define BATCH  2
#define S_LEN  2048
#define DMODEL 1024
#define NH     16
#define DHEAD  64

typedef __attribute__((ext_vector_type(8))) short bf16x8;   // 8 bf16 = 4 VGPRs
typedef __attribute__((ext_vector_type(4))) float f32x4;

#define MFMA16(a,b,c) __builtin_amdgcn_mfma_f32_16x16x32_bf16((a),(b),(c),0,0,0)

// Q pre-scale: (1/sqrt(64)) * log2(e) so attention uses exp2 directly
#define QSCALE 0.18033688011110793f
#define EXP2F(x) __builtin_amdgcn_exp2f(x)

__device__ __forceinline__ unsigned int pkbf(float a, float b) {
    __hip_bfloat162 h = __float22bfloat162_rn(make_float2(a, b));
    union { __hip_bfloat162 h; unsigned int u; } v; v.h = h; return v.u;
}
__device__ __forceinline__ void gl2lds16(const void* g, void* l) {
    __builtin_amdgcn_global_load_lds(
        (const __attribute__((address_space(1))) void*)(g),
        (__attribute__((address_space(3))) void*)(l), 16, 0, 0);
}

// ---------------------------------------------------------------------------
// Single fused fp32->bf16 convert for Q, W_Q|W_K|W_V, mask. 8 elems/unit.
// ---------------------------------------------------------------------------
__global__ __launch_bounds__(256) void cvt_all(
    const float* __restrict__ Q,  const float* __restrict__ WQ,
    const float* __restrict__ WK, const float* __restrict__ WV,
    const float* __restrict__ msk,
    unsigned short* __restrict__ Qbf, unsigned short* __restrict__ Wbf,
    unsigned short* __restrict__ mbf)
{
    int i = blockIdx.x * blockDim.x + threadIdx.x;   // grid covers 918016 units
    const float* src;
    unsigned short* dst;
    int off;
    if (i < 524288) {
        src = Q; dst = Qbf; off = i;
    } else if (i < 917504) {
        int j = i - 524288;                  // [0, 393216)
        int which = j >> 17;                 // /131072
        src = (which == 0) ? WQ : ((which == 1) ? WK : WV);
        dst = Wbf + ((size_t)which << 20);   // which * 1048576
        off = j & 131071;
    } else {
        int j = i - 917504;
        if (j >= 512) return;
        src = msk; dst = mbf; off = j;
    }
    float4 a = ((const float4*)src)[2*off];
    float4 b = ((const float4*)src)[2*off + 1];
    uint4 o;
    o.x = pkbf(a.x, a.y); o.y = pkbf(a.z, a.w);
    o.z = pkbf(b.x, b.y); o.w = pkbf(b.z, b.w);
    ((uint4*)dst)[off] = o;
}

// ---------------------------------------------------------------------------
// Projection GEMM with folds (unchanged):
//   z=0 -> qw [b,h,s,dk] *QSCALE ; z=1 -> kw ; z=2 -> vt [b,h,dv,s] * mask
// 128x128 tile, BK=64, dbuf LDS, XOR-swizzle, XCD-bijective remap.
// ---------------------------------------------------------------------------
__global__ __launch_bounds__(256) void proj_mfma(
    const unsigned short* __restrict__ Abf,   // [4096][1024]
    const unsigned short* __restrict__ Wbf,   // [3][1024][1024]
    const float* __restrict__ bQ, const float* __restrict__ bK,
    const float* __restrict__ bV, const float* __restrict__ mask,
    unsigned short* __restrict__ qw, unsigned short* __restrict__ kw,
    unsigned short* __restrict__ vt)
{
    __shared__ union {
        struct { unsigned short At[2][128*64]; unsigned short Bt[2][128*64]; } s; // 64 KB
        unsigned short Ct[128*132];     // epilogue transpose tile (33.8 KB, aliased)
    } sm;

    const int tid  = threadIdx.x;
    const int lane = tid & 63;
    const int wv   = tid >> 6;
    const int wm   = (wv >> 1) * 64;
    const int wn   = (wv & 1) * 64;
    const int q15  = lane & 15;
    const int quad = lane >> 4;

    const int f  = blockIdx.x + (blockIdx.y << 3) + (blockIdx.z << 8);
    const int l  = (f & 7) * 96 + (f >> 3);
    const int z  = l >> 8;
    const int lr = l & 255;
    const int n0 = (lr & 7) * 128;
    const int m0 = (lr >> 3) * 128;

    const unsigned short* Wz = Wbf + (size_t)z * DMODEL * DMODEL;
    const float* bias = (z == 0) ? bQ : ((z == 1) ? bK : bV);

    f32x4 zero4 = {0.f, 0.f, 0.f, 0.f};
    f32x4 acc[4][4];
    #pragma unroll
    for (int i = 0; i < 4; ++i)
        #pragma unroll
        for (int j = 0; j < 4; ++j) acc[i][j] = zero4;

    #define STAGE_PROJ(BUF, K0)                                                \
        _Pragma("unroll")                                                      \
        for (int c = 0; c < 4; ++c) {                                          \
            int o   = tid * 16 + c * 4096;                                     \
            int row = o >> 7;                                                  \
            int lb  = (o & 127) ^ ((row & 7) << 4);                            \
            gl2lds16(Abf + (size_t)(m0 + row) * DMODEL + (K0) + (lb >> 1),     \
                     (char*)sm.s.At[BUF] + o);                                 \
            gl2lds16(Wz  + (size_t)(n0 + row) * DMODEL + (K0) + (lb >> 1),     \
                     (char*)sm.s.Bt[BUF] + o);                                 \
        }

    STAGE_PROJ(0, 0)
    __syncthreads();

    const int sw = (q15 & 7) << 4;

    for (int t = 0; t < 16; ++t) {
        const int buf = t & 1;
        if (t < 15) { STAGE_PROJ(buf ^ 1, (t + 1) * 64) }

        bf16x8 af[4][2], bfr[4][2];
        #pragma unroll
        for (int i = 0; i < 4; ++i) {
            const char* pa = (const char*)sm.s.At[buf] + (wm + i*16 + q15) * 128;
            const char* pb = (const char*)sm.s.Bt[buf] + (wn + i*16 + q15) * 128;
            af[i][0]  = *(const bf16x8*)(pa + (( 0 + quad*16) ^ sw));
            af[i][1]  = *(const bf16x8*)(pa + ((64 + quad*16) ^ sw));
            bfr[i][0] = *(const bf16x8*)(pb + (( 0 + quad*16) ^ sw));
            bfr[i][1] = *(const bf16x8*)(pb + ((64 + quad*16) ^ sw));
        }

        if (z < 2) {
            #pragma unroll
            for (int ks = 0; ks < 2; ++ks)
                #pragma unroll
                for (int i = 0; i < 4; ++i)
                    #pragma unroll
                    for (int j = 0; j < 4; ++j)
                        acc[i][j] = MFMA16(bfr[j][ks], af[i][ks], acc[i][j]);
        } else {
            #pragma unroll
            for (int ks = 0; ks < 2; ++ks)
                #pragma unroll
                for (int i = 0; i < 4; ++i)
                    #pragma unroll
                    for (int j = 0; j < 4; ++j)
                        acc[i][j] = MFMA16(af[i][ks], bfr[j][ks], acc[i][j]);
        }
        __syncthreads();
    }
    #undef STAGE_PROJ

    if (z < 2) {
        const float qs = (z == 0) ? QSCALE : 1.0f;
        #pragma unroll
        for (int i = 0; i < 4; ++i) {
            int ml = wm + i*16 + q15;
            #pragma unroll
            for (int j = 0; j < 4; ++j) {
                int nl = wn + j*16 + quad*4;
                float4 b4 = *(const float4*)(bias + n0 + nl);
                f32x4 v = acc[i][j];
                uint2 u;
                u.x = pkbf((v.x + b4.x)*qs, (v.y + b4.y)*qs);
                u.y = pkbf((v.z + b4.z)*qs, (v.w + b4.w)*qs);
                *(uint2*)&sm.Ct[ml*132 + nl] = u;
            }
        }
    } else {
        #pragma unroll
        for (int i = 0; i < 4; ++i) {
            int ml = wm + i*16 + quad*4;
            int sg = m0 + ml;
            int b2 = sg >> 11, s0g = sg & 2047;
            float4 mk4 = *(const float4*)(mask + (size_t)b2*S_LEN + s0g);
            #pragma unroll
            for (int j = 0; j < 4; ++j) {
                int nl = wn + j*16 + q15;
                float bv = bias[n0 + nl];
                f32x4 v = acc[i][j];
                uint2 u;
                u.x = pkbf((v.x + bv)*mk4.x, (v.y + bv)*mk4.y);
                u.y = pkbf((v.z + bv)*mk4.z, (v.w + bv)*mk4.w);
                *(uint2*)&sm.Ct[nl*132 + ml] = u;
            }
        }
    }
    __syncthreads();

    {
        int row  = tid >> 1;
        int half = (tid & 1) * 64;
        const uint4* src = (const uint4*)&sm.Ct[row*132 + half];
        unsigned short* dst;
        if (z < 2) {
            unsigned short* outp = (z == 0) ? qw : kw;
            int mg = m0 + row;  int b2 = mg >> 11, s = mg & 2047;
            int n  = n0 + half; int hh = n >> 6;
            dst = outp + (((size_t)b2*NH + hh)*S_LEN + s)*DHEAD;
        } else {
            int n  = n0 + row;  int hh = n >> 6, dv = n & 63;
            int b2 = m0 >> 11, s0 = m0 & 2047;
            dst = vt + (((size_t)b2*NH + hh)*DHEAD + dv)*S_LEN + s0 + half;
        }
        #pragma unroll
        for (int c = 0; c < 8; ++c) ((uint4*)dst)[c] = src[c];
    }
}

// ---------------------------------------------------------------------------
// Attention v7: r6's conflict-free gl2lds staging + DEFERRED-PV pipeline.
// r6 counters showed pipes SUMMING (MFMA 15 + VALU 20 + LDS 21 ~= wall 56us):
// per-wave serial chain QK_t -> exp_t -> PV_t with 2 waves/SIMD = no overlap.
// v7 body t: QK_t (MFMA) ; PV_{t-1}+den_{t-1} (MFMA, regs only) ; exp_t (VALU).
// exp_t overlaps PV_{t-1}'s MFMA drain; QK_{t+1} never waits on exp/PV.
// V_t fragments are read into REGS during body t (safe buffer) and consumed
// in body t+1 -> no race with the prefetch overwriting buf^1, and PV reads
// no LDS. P/V/register sets ping-pong via named A/B sets (no runtime idx).
// Volumes identical to r6; pure schedule change.
// ---------------------------------------------------------------------------
__global__ __launch_bounds__(256, 2) void attn_mfma(
    const unsigned short* __restrict__ qw, const unsigned short* __restrict__ kw,
    const unsigned short* __restrict__ vt, const unsigned short* __restrict__ mbf,
    float* __restrict__ out)
{
    __shared__ __align__(16) unsigned short Ks[2][64][64];   // swizzled, 16 KB
    __shared__ __align__(16) unsigned short Vs[2][64][64];   // swizzled, 16 KB

    const int tid  = threadIdx.x;
    const int lane = tid & 63;
    const int wv   = tid >> 6;
    const int q15  = lane & 15;
    const int quad = lane >> 4;

    // XCD-bijective remap (512 = 8 XCDs x 64): XCD c owns heads [c*4, c*4+4).
    const int orig = blockIdx.x + (blockIdx.y << 4) + (blockIdx.z << 8);
    const int lid  = (orig & 7) * 64 + (orig >> 3);
    const int q0   = (lid & 15) * 128;
    const int head = lid >> 4;          // [0,32)
    const int h    = head & 15;
    const int b    = head >> 4;

    const size_t headoff = ((size_t)b * NH + h) * S_LEN * DHEAD;
    const unsigned short* qb = qw + headoff;
    const unsigned short* kb = kw + headoff;
    const unsigned short* vb = vt + headoff;          // [dv][s]
    const unsigned short* mb = mbf + (size_t)b * S_LEN;

    // Q fragments (B-operand): B[k=d at quad*8+j][n=query at lane&15]
    bf16x8 qf[2][2];
    #pragma unroll
    for (int qi = 0; qi < 2; ++qi) {
        const unsigned short* qr = qb + (size_t)(q0 + wv*32 + qi*16 + q15)*DHEAD;
        qf[qi][0] = *(const bf16x8*)(qr + quad*8);
        qf[qi][1] = *(const bf16x8*)(qr + 32 + quad*8);
    }

    // Staging addressing: dest byte o = tid*16 (c=0), +4096 (c=1); row = o>>7.
    // Physical byte p of row r holds logical byte p ^ ((r&7)<<4).
    const int srow = tid >> 3;                        // 0..31
    const int kap  = (srow & 3) | (((srow >> 4) & 1) << 2) | (((srow >> 2) & 3) << 3);
    const int lb   = ((tid & 7) * 16) ^ ((srow & 7) << 4);
    const unsigned short* ksrc0 = kb + (size_t)kap        * DHEAD + (lb >> 1);
    const unsigned short* ksrc1 = kb + (size_t)(kap + 32) * DHEAD + (lb >> 1);
    const unsigned short* vsrc0 = vb + (size_t)srow        * S_LEN + (lb >> 1);
    const unsigned short* vsrc1 = vb + (size_t)(srow + 32) * S_LEN + (lb >> 1);
    char* kdst = (char*)&Ks[0][0][0] + tid * 16;      // c=0; c=1 at +4096
    char* vdst = (char*)&Vs[0][0][0] + tid * 16;
    const int sw = (q15 & 7) << 4;                    // read-side swizzle

    f32x4 zero4 = {0.f, 0.f, 0.f, 0.f};
    f32x4 oacc[2][4];
    f32x4 dacc[2];
    #pragma unroll
    for (int qi = 0; qi < 2; ++qi) {
        dacc[qi] = zero4;
        #pragma unroll
        for (int nj = 0; nj < 4; ++nj) oacc[qi][nj] = zero4;
    }

    // Named ping-pong register sets (rule #20: static indexing only)
    bf16x8 pfA[2][2], pfB[2][2];
    bf16x8 vfA[4][2], vfB[4][2];

    // Body T: QK_T ; PV_{T-1} (from PFP/VFP regs) ; exp_T -> PFN; V_T -> VFN.
    // Prefetch tile T+1 issued early; ONE barrier at body end drains it.
    #define ATTN_BODY(T, BUF, PFP, VFP, PFN, VFN, DOPV, DOPREF)                 \
    {                                                                           \
        const char* kbase = (const char*)&Ks[0][0][0] + (BUF) * 8192;           \
        const char* vbase = (const char*)&Vs[0][0][0] + (BUF) * 8192;           \
        _Pragma("unroll")                                                       \
        for (int nj = 0; nj < 4; ++nj) {                                        \
            const char* vrp = vbase + (nj*16 + q15) * 128;                      \
            VFN[nj][0] = *(const bf16x8*)(vrp + (( 0 + quad*16) ^ sw));         \
            VFN[nj][1] = *(const bf16x8*)(vrp + ((64 + quad*16) ^ sw));         \
        }                                                                       \
        if (DOPREF) {                                                           \
            const int kn = ((T) + 1) * 64;                                      \
            const int ob = ((BUF) ^ 1) * 8192;                                  \
            gl2lds16(ksrc0 + (size_t)kn * DHEAD, kdst + ob);                    \
            gl2lds16(ksrc1 + (size_t)kn * DHEAD, kdst + ob + 4096);             \
            gl2lds16(vsrc0 + kn, vdst + ob);                                    \
            gl2lds16(vsrc1 + kn, vdst + ob + 4096);                             \
        }                                                                       \
        bf16x8 mp0, mp1;                                                        \
        if (DOPV) {                                                             \
            mp0 = *(const bf16x8*)(mb + ((T)-1)*64 + quad*8);                   \
            mp1 = *(const bf16x8*)(mb + ((T)-1)*64 + 32 + quad*8);              \
        }                                                                       \
        f32x4 s[2][4];                                                          \
        __builtin_amdgcn_s_setprio(1);                                          \
        _Pragma("unroll")                                                       \
        for (int ks = 0; ks < 4; ++ks) {                                        \
            const char* krp = kbase + (ks*16 + q15) * 128;                      \
            bf16x8 kf0 = *(const bf16x8*)(krp + (( 0 + quad*16) ^ sw));         \
            bf16x8 kf1 = *(const bf16x8*)(krp + ((64 + quad*16) ^ sw));         \
            _Pragma("unroll")                                                   \
            for (int qi = 0; qi < 2; ++qi) {                                    \
                f32x4 a = MFMA16(kf0, qf[qi][0], zero4);                        \
                s[qi][ks] = MFMA16(kf1, qf[qi][1], a);                          \
            }                                                                   \
        }                                                                       \
        if (DOPV) {                                                             \
            _Pragma("unroll")                                                   \
            for (int qi = 0; qi < 2; ++qi) {                                    \
                dacc[qi] = MFMA16(PFP[qi][0], mp0, dacc[qi]);                   \
                dacc[qi] = MFMA16(PFP[qi][1], mp1, dacc[qi]);                   \
            }                                                                   \
            _Pragma("unroll")                                                   \
            for (int nj = 0; nj < 4; ++nj)                                      \
                _Pragma("unroll")                                               \
                for (int qi = 0; qi < 2; ++qi) {                                \
                    oacc[qi][nj] = MFMA16(PFP[qi][0], VFP[nj][0], oacc[qi][nj]);\
                    oacc[qi][nj] = MFMA16(PFP[qi][1], VFP[nj][1], oacc[qi][nj]);\
                }                                                               \
        }                                                                       \
        __builtin_amdgcn_s_setprio(0);                                          \
        _Pragma("unroll")                                                       \
        for (int qi = 0; qi < 2; ++qi) {                                        \
            uint4 u0, u1;                                                       \
            u0.x = pkbf(EXP2F(s[qi][0][0]), EXP2F(s[qi][0][1]));                \
            u0.y = pkbf(EXP2F(s[qi][0][2]), EXP2F(s[qi][0][3]));                \
            u0.z = pkbf(EXP2F(s[qi][1][0]), EXP2F(s[qi][1][1]));                \
            u0.w = pkbf(EXP2F(s[qi][1][2]), EXP2F(s[qi][1][3]));                \
            u1.x = pkbf(EXP2F(s[qi][2][0]), EXP2F(s[qi][2][1]));                \
            u1.y = pkbf(EXP2F(s[qi][2][2]), EXP2F(s[qi][2][3]));                \
            u1.z = pkbf(EXP2F(s[qi][3][0]), EXP2F(s[qi][3][1]));                \
            u1.w = pkbf(EXP2F(s[qi][3][2]), EXP2F(s[qi][3][3]));                \
            union { uint4 u; bf16x8 hh; } c0, c1;                               \
            c0.u = u0; c1.u = u1;                                               \
            PFN[qi][0] = c0.hh;                                                 \
            PFN[qi][1] = c1.hh;                                                 \
        }                                                                       \
        __syncthreads();                                                        \
    }

    // prologue: stage tile 0 into buf 0
    gl2lds16(ksrc0, kdst);
    gl2lds16(ksrc1, kdst + 4096);
    gl2lds16(vsrc0, vdst);
    gl2lds16(vsrc1, vdst + 4096);
    __syncthreads();

    // t=0: produce set A (no PV yet); prefetch tile 1
    ATTN_BODY(0, 0, pfB, vfB, pfA, vfA, 0, 1)

    // pairs (1,2),(3,4),...,(29,30): A->B then B->A; always prefetch
    for (int t = 1; t < 31; t += 2) {
        ATTN_BODY(t,     1, pfA, vfA, pfB, vfB, 1, 1)
        ATTN_BODY(t + 1, 0, pfB, vfB, pfA, vfA, 1, 1)
    }

    // t=31: A->B; no prefetch
    ATTN_BODY(31, 1, pfA, vfA, pfB, vfB, 1, 0)
    #undef ATTN_BODY

    // drain: PV_31 + den_31 from pfB/vfB, mask tile 31
    {
        bf16x8 mp0 = *(const bf16x8*)(mb + 31*64 + quad*8);
        bf16x8 mp1 = *(const bf16x8*)(mb + 31*64 + 32 + quad*8);
        #pragma unroll
        for (int qi = 0; qi < 2; ++qi) {
            dacc[qi] = MFMA16(pfB[qi][0], mp0, dacc[qi]);
            dacc[qi] = MFMA16(pfB[qi][1], mp1, dacc[qi]);
        }
        #pragma unroll
        for (int nj = 0; nj < 4; ++nj)
            #pragma unroll
            for (int qi = 0; qi < 2; ++qi) {
                oacc[qi][nj] = MFMA16(pfB[qi][0], vfB[nj][0], oacc[qi][nj]);
                oacc[qi][nj] = MFMA16(pfB[qi][1], vfB[nj][1], oacc[qi][nj]);
            }
    }

    // epilogue: D rows quad*4+r = query; denom replicated across n lanes
    #pragma unroll
    for (int qi = 0; qi < 2; ++qi)
        #pragma unroll
        for (int r = 0; r < 4; ++r) {
            float inv = 1.0f / (dacc[qi][r] + 1e-8f);
            size_t row = ((size_t)b*S_LEN + q0 + wv*32 + qi*16 + quad*4 + r)*DMODEL
                       + h*DHEAD;
            #pragma unroll
            for (int nj = 0; nj < 4; ++nj)
                out[row + nj*16 + q15] = oacc[qi][nj][r] * inv;
        }
}

// ---------------------------------------------------------------------------
extern "C" void kernel_launch(void* const* d_in, const int* in_sizes, int n_in,
                              void* d_out, int out_size, void* d_ws, size_t ws_size,
                              hipStream_t stream) {
    const float* Q    = (const float*)d_in[0];
    const float* msk  = (const float*)d_in[1];
    const float* W_Q  = (const float*)d_in[2];
    const float* b_Q  = (const float*)d_in[3];
    const float* W_K  = (const float*)d_in[4];
    const float* b_K  = (const float*)d_in[5];
    const float* W_V  = (const float*)d_in[6];
    const float* b_V  = (const float*)d_in[7];
    float* out = (float*)d_out;

    unsigned short* wsu = (unsigned short*)d_ws;
    unsigned short* Qbf = wsu;                                   // 4M elems
    unsigned short* Wbf = Qbf + (size_t)4096*1024;               // 3M
    unsigned short* qwb = Wbf + (size_t)3*1024*1024;             // 4M
    unsigned short* kwb = qwb + (size_t)4*1024*1024;             // 4M
    unsigned short* vtb = kwb + (size_t)4*1024*1024;             // 4M
    unsigned short* mbf = vtb + (size_t)4*1024*1024;             // 4K

    cvt_all<<<3586, 256, 0, stream>>>(Q, W_Q, W_K, W_V, msk, Qbf, Wbf, mbf);

    proj_mfma<<<dim3(8, 32, 3), 256, 0, stream>>>(
        Qbf, Wbf, b_Q, b_K, b_V, msk, qwb, kwb, vtb);

    attn_mfma<<<dim3(S_LEN/128, NH, BATCH), 256, 0, stream>>>(
        qwb, kwb, vtb, mbf, out);
}